// Round 1
// baseline (442.217 us; speedup 1.0000x reference)
//
#include <hip/hip_runtime.h>

typedef unsigned short u16;
typedef __attribute__((ext_vector_type(8))) short bf16x8;
typedef __attribute__((ext_vector_type(4))) float f32x4;

__device__ __forceinline__ u16 f2bf(float f) {
  union { float fv; unsigned u; } v; v.fv = f;
  unsigned r = v.u + 0x7fffu + ((v.u >> 16) & 1u);
  return (u16)(r >> 16);
}

__device__ __forceinline__ void gload_lds16(const void* g, void* l) {
  __builtin_amdgcn_global_load_lds(
      (const __attribute__((address_space(1))) unsigned*)g,
      (__attribute__((address_space(3))) unsigned*)l, 16, 0, 0);
}

// ---- elementwise f32 -> bf16 (4 elems/thread) -------------------------------
__global__ __launch_bounds__(256) void cvt_bf16_kernel(const float* __restrict__ x,
                                                       u16* __restrict__ y) {
  const int i = (blockIdx.x * 256 + threadIdx.x) * 4;
  const float4 v = *(const float4*)(x + i);
  ushort4 o;
  o.x = f2bf(v.x); o.y = f2bf(v.y); o.z = f2bf(v.z); o.w = f2bf(v.w);
  *(ushort4*)(y + i) = o;
}

// ---- W (1024 x 1024 f32, k-major) -> WT (n-major bf16) ----------------------
__global__ __launch_bounds__(256) void transpose_cvt_kernel(const float* __restrict__ W,
                                                            u16* __restrict__ WT) {
  __shared__ float tile[32][33];
  const int bx = blockIdx.x * 32, by = blockIdx.y * 32;
  const int tx = threadIdx.x, ty = threadIdx.y;
  #pragma unroll
  for (int i = 0; i < 32; i += 8)
    tile[ty + i][tx] = W[(size_t)(by + ty + i) * 1024 + bx + tx];
  __syncthreads();
  #pragma unroll
  for (int i = 0; i < 32; i += 8)
    WT[(size_t)(bx + ty + i) * 1024 + by + tx] = f2bf(tile[tx][ty + i]);
}

// ---- 128x128 tile GEMM, A (M x 1024) bf16, BT (1024 x 1024) bf16 ------------
// MODE 0: q -> (B,H,T,64) bf16, scaled by 1/8 ; MODE 1: k -> (B,H,T,64)
// MODE 2: v -> (B,H,64,T) transposed        ; MODE 3: f32 out + bias
template <int MODE>
__global__ __launch_bounds__(256) void gemm128_kernel(
    const u16* __restrict__ A, const u16* __restrict__ BT,
    const float* __restrict__ bias, void* __restrict__ out) {
  __shared__ u16 As[128 * 32];
  __shared__ u16 Bs[128 * 32];
  const int tid = threadIdx.x;
  const int w = tid >> 6, lane = tid & 63;
  const int wr = w >> 1, wc = w & 1;
  const int l16 = lane & 15, lhi = lane >> 4;
  const int m0 = blockIdx.y * 128, n0 = blockIdx.x * 128;

  f32x4 acc[4][4] = {};

  for (int kt = 0; kt < 32; ++kt) {
    #pragma unroll
    for (int i = 0; i < 2; ++i) {
      const int ob = w * 2048 + i * 1024;      // wave-uniform LDS byte base
      const int o = ob + (lane << 4);          // this lane's byte offset
      const int row = o >> 6, kbyte = o & 63;  // [128][32] bf16: 64B rows
      gload_lds16((const char*)A + (((size_t)(m0 + row)) << 11) + (kt << 6) + kbyte,
                  (char*)As + ob);
      gload_lds16((const char*)BT + (((size_t)(n0 + row)) << 11) + (kt << 6) + kbyte,
                  (char*)Bs + ob);
    }
    __syncthreads();
    bf16x8 a[4], b[4];
    #pragma unroll
    for (int i = 0; i < 4; ++i)
      a[i] = *(const bf16x8*)(As + (wr * 64 + i * 16 + l16) * 32 + lhi * 8);
    #pragma unroll
    for (int j = 0; j < 4; ++j)
      b[j] = *(const bf16x8*)(Bs + (wc * 64 + j * 16 + l16) * 32 + lhi * 8);
    #pragma unroll
    for (int i = 0; i < 4; ++i)
      #pragma unroll
      for (int j = 0; j < 4; ++j)
        acc[i][j] = __builtin_amdgcn_mfma_f32_16x16x32_bf16(a[i], b[j], acc[i][j], 0, 0, 0);
    __syncthreads();
  }

  #pragma unroll
  for (int i = 0; i < 4; ++i) {
    #pragma unroll
    for (int j = 0; j < 4; ++j) {
      const int n = n0 + wc * 64 + j * 16 + l16;
      const float bn = bias[n];
      #pragma unroll
      for (int r = 0; r < 4; ++r) {
        const int m = m0 + wr * 64 + i * 16 + lhi * 4 + r;
        float v = acc[i][j][r] + bn;
        const int bb = m >> 11, t = m & 2047, h = n >> 6, d = n & 63;
        if constexpr (MODE == 0) {
          v *= 0.125f;  // fold 1/sqrt(DK) into q
          ((u16*)out)[((((size_t)bb * 16 + h) * 2048 + t) << 6) + d] = f2bf(v);
        } else if constexpr (MODE == 1) {
          ((u16*)out)[((((size_t)bb * 16 + h) * 2048 + t) << 6) + d] = f2bf(v);
        } else if constexpr (MODE == 2) {
          ((u16*)out)[(((size_t)bb * 16 + h) * 64 + d) * 2048 + t] = f2bf(v);
        } else {
          ((float*)out)[(size_t)m * 1024 + n] = v;
        }
      }
    }
  }
}

// ---- flash attention: 1 block = (b, h, 64 q-rows); 4 waves x 16 rows --------
__global__ __launch_bounds__(256) void attn_kernel(
    const u16* __restrict__ qh, const u16* __restrict__ kh,
    const u16* __restrict__ vth, u16* __restrict__ outPre) {
  __shared__ u16 Kt[64 * 64];     // [key][d]
  __shared__ u16 Vt[64 * 64];     // [d][key]
  __shared__ u16 Pl[4][16 * 64];  // per-wave P tile [qrow][key]

  const int tid = threadIdx.x, w = tid >> 6, lane = tid & 63;
  const int l16 = lane & 15, lhi = lane >> 4;
  const int qt = blockIdx.x, h = blockIdx.y, b = blockIdx.z;
  const size_t bh = (size_t)b * 16 + h;
  const u16* qb = qh + bh * (2048 * 64);
  const u16* kb = kh + bh * (2048 * 64);
  const u16* vb = vth + bh * (64 * 2048);

  const int qr0 = qt * 64 + w * 16;
  bf16x8 aq[2];
  #pragma unroll
  for (int c = 0; c < 2; ++c)
    aq[c] = *(const bf16x8*)(qb + (qr0 + l16) * 64 + c * 32 + lhi * 8);

  f32x4 acc_o[4] = {};
  float mrow[4] = {-1e30f, -1e30f, -1e30f, -1e30f};
  float lrow[4] = {0.f, 0.f, 0.f, 0.f};

  for (int kv = 0; kv < 2048; kv += 64) {
    #pragma unroll
    for (int i = 0; i < 2; ++i) {
      const int ob = w * 2048 + i * 1024;
      const int o = ob + (lane << 4);
      // K tile: contiguous 8KB in (B,H,T,64)
      gload_lds16((const char*)kb + ((size_t)kv << 7) + o, (char*)Kt + ob);
      // V^T tile: row d (stride T*2B), cols kv..kv+63
      const int dd = o >> 7, j0 = (o & 127) >> 1;
      gload_lds16((const char*)vb + ((size_t)dd << 12) + (((size_t)(kv + j0)) << 1),
                  (char*)Vt + ob);
    }
    __syncthreads();

    // S = q . k^T   (q pre-scaled by 1/8)
    f32x4 s[4] = {};
    #pragma unroll
    for (int c = 0; c < 2; ++c) {
      #pragma unroll
      for (int jt = 0; jt < 4; ++jt) {
        const bf16x8 bk = *(const bf16x8*)(Kt + (jt * 16 + l16) * 64 + c * 32 + lhi * 8);
        s[jt] = __builtin_amdgcn_mfma_f32_16x16x32_bf16(aq[c], bk, s[jt], 0, 0, 0);
      }
    }

    // online softmax; row i = (lane>>4)*4 + r, reduce across 16 lanes
    #pragma unroll
    for (int r = 0; r < 4; ++r) {
      float mx = fmaxf(fmaxf(s[0][r], s[1][r]), fmaxf(s[2][r], s[3][r]));
      #pragma unroll
      for (int dx = 1; dx < 16; dx <<= 1) mx = fmaxf(mx, __shfl_xor(mx, dx));
      const float mnew = fmaxf(mrow[r], mx);
      const float scale = __expf(mrow[r] - mnew);
      float ps = 0.f;
      #pragma unroll
      for (int jt = 0; jt < 4; ++jt) {
        const float p = __expf(s[jt][r] - mnew);
        s[jt][r] = p;
        ps += p;
      }
      #pragma unroll
      for (int dx = 1; dx < 16; dx <<= 1) ps += __shfl_xor(ps, dx);
      lrow[r] = lrow[r] * scale + ps;
      mrow[r] = mnew;
      #pragma unroll
      for (int dt = 0; dt < 4; ++dt) acc_o[dt][r] *= scale;
    }

    // P -> LDS (D-layout -> A-layout transpose via LDS)
    #pragma unroll
    for (int jt = 0; jt < 4; ++jt)
      #pragma unroll
      for (int r = 0; r < 4; ++r)
        Pl[w][(lhi * 4 + r) * 64 + jt * 16 + l16] = f2bf(s[jt][r]);

    __syncthreads();

    // O += P @ V
    #pragma unroll
    for (int c = 0; c < 2; ++c) {
      const bf16x8 ap = *(const bf16x8*)(&Pl[w][l16 * 64 + c * 32 + lhi * 8]);
      #pragma unroll
      for (int dt = 0; dt < 4; ++dt) {
        const bf16x8 bv = *(const bf16x8*)(Vt + (dt * 16 + l16) * 64 + c * 32 + lhi * 8);
        acc_o[dt] = __builtin_amdgcn_mfma_f32_16x16x32_bf16(ap, bv, acc_o[dt], 0, 0, 0);
      }
    }
    __syncthreads();
  }

  // write into the faithful-reshape layout: row = h*128 + t/16, col = (t%16)*64 + d
  #pragma unroll
  for (int dt = 0; dt < 4; ++dt) {
    #pragma unroll
    for (int r = 0; r < 4; ++r) {
      const int t = qr0 + lhi * 4 + r;
      const int d = dt * 16 + l16;
      const float v = acc_o[dt][r] / lrow[r];
      const int rr = h * 128 + (t >> 4);
      const int cc = ((t & 15) << 6) + d;
      outPre[((size_t)b * 2048 + rr) * 1024 + cc] = f2bf(v);
    }
  }
}

extern "C" void kernel_launch(void* const* d_in, const int* in_sizes, int n_in,
                              void* d_out, int out_size, void* d_ws, size_t ws_size,
                              hipStream_t stream) {
  const float* Q  = (const float*)d_in[0];
  const float* K  = (const float*)d_in[1];
  const float* V  = (const float*)d_in[2];
  const float* Wq = (const float*)d_in[3];
  const float* bq = (const float*)d_in[4];
  const float* Wk = (const float*)d_in[5];
  const float* bk = (const float*)d_in[6];
  const float* Wv = (const float*)d_in[7];
  const float* bv = (const float*)d_in[8];
  const float* Wo = (const float*)d_in[9];
  const float* bo = (const float*)d_in[10];

  char* ws = (char*)d_ws;
  const size_t ACT = 16777216;              // 8192*1024 bf16
  u16* act = (u16*)(ws);                    // reused: Qbf/Kbf/Vbf, then outPre
  u16* qhd = (u16*)(ws + ACT);
  u16* khd = (u16*)(ws + 2 * ACT);
  u16* vtd = (u16*)(ws + 3 * ACT);
  u16* wt  = (u16*)(ws + 4 * ACT);          // 2MB transposed weight

  const dim3 tb(32, 8), tg(32, 32);
  const dim3 gg(8, 64);                     // (N/128, M/128)
  const int cvtBlocks = 8388608 / 4 / 256;

  // q = (Q@Wq + bq)/8
  transpose_cvt_kernel<<<tg, tb, 0, stream>>>(Wq, wt);
  cvt_bf16_kernel<<<cvtBlocks, 256, 0, stream>>>(Q, act);
  gemm128_kernel<0><<<gg, 256, 0, stream>>>(act, wt, bq, qhd);
  // k
  transpose_cvt_kernel<<<tg, tb, 0, stream>>>(Wk, wt);
  cvt_bf16_kernel<<<cvtBlocks, 256, 0, stream>>>(K, act);
  gemm128_kernel<1><<<gg, 256, 0, stream>>>(act, wt, bk, khd);
  // v (stored transposed per head)
  transpose_cvt_kernel<<<tg, tb, 0, stream>>>(Wv, wt);
  cvt_bf16_kernel<<<cvtBlocks, 256, 0, stream>>>(V, act);
  gemm128_kernel<2><<<gg, 256, 0, stream>>>(act, wt, bv, vtd);
  // attention -> outPre (reuses act)
  attn_kernel<<<dim3(32, 16, 4), 256, 0, stream>>>(qhd, khd, vtd, act);
  // out = outPre @ Wo + bo (f32)
  transpose_cvt_kernel<<<tg, tb, 0, stream>>>(Wo, wt);
  gemm128_kernel<3><<<gg, 256, 0, stream>>>(act, wt, bo, (float*)d_out);
}

// Round 2
// 394.896 us; speedup vs baseline: 1.1198x; 1.1198x over previous
//
#include <hip/hip_runtime.h>

typedef unsigned short u16;
typedef __attribute__((ext_vector_type(8))) short bf16x8;
typedef __attribute__((ext_vector_type(4))) float f32x4;

__device__ __forceinline__ u16 f2bf(float f) {
  union { float fv; unsigned u; } v; v.fv = f;
  unsigned r = v.u + 0x7fffu + ((v.u >> 16) & 1u);
  return (u16)(r >> 16);
}

__device__ __forceinline__ void gload_lds16(const void* g, void* l) {
  __builtin_amdgcn_global_load_lds(
      (const __attribute__((address_space(1))) unsigned*)g,
      (__attribute__((address_space(3))) unsigned*)l, 16, 0, 0);
}

// XOR-swizzle for LDS tiles with 128B rows: spreads the column slice of
// 8 consecutive rows across 8 distinct 16B slots (32 banks). Involution.
__device__ __forceinline__ int swz128(int o) { return o ^ ((o >> 3) & 0x70); }

// ---- elementwise f32 -> bf16 (4 elems/thread) -------------------------------
__global__ __launch_bounds__(256) void cvt_bf16_kernel(const float* __restrict__ x,
                                                       u16* __restrict__ y) {
  const int i = (blockIdx.x * 256 + threadIdx.x) * 4;
  const float4 v = *(const float4*)(x + i);
  ushort4 o;
  o.x = f2bf(v.x); o.y = f2bf(v.y); o.z = f2bf(v.z); o.w = f2bf(v.w);
  *(ushort4*)(y + i) = o;
}

// ---- W (1024 x 1024 f32, k-major) -> WT (n-major bf16) ----------------------
__global__ __launch_bounds__(256) void transpose_cvt_kernel(const float* __restrict__ W,
                                                            u16* __restrict__ WT) {
  __shared__ float tile[32][33];
  const int bx = blockIdx.x * 32, by = blockIdx.y * 32;
  const int tx = threadIdx.x, ty = threadIdx.y;
  #pragma unroll
  for (int i = 0; i < 32; i += 8)
    tile[ty + i][tx] = W[(size_t)(by + ty + i) * 1024 + bx + tx];
  __syncthreads();
  #pragma unroll
  for (int i = 0; i < 32; i += 8)
    WT[(size_t)(bx + ty + i) * 1024 + by + tx] = f2bf(tile[tx][ty + i]);
}

// ---- 128x128 tile GEMM, A (M x 1024) bf16, BT (1024 x 1024) bf16 ------------
// MODE 0: q -> (B,H,T,64) bf16, scaled by 1/8 ; MODE 1: k -> (B,H,T,64)
// MODE 2: v -> (B,H,64,T) transposed        ; MODE 3: f32 out + bias
template <int MODE>
__global__ __launch_bounds__(256) void gemm128_kernel(
    const u16* __restrict__ A, const u16* __restrict__ BT,
    const float* __restrict__ bias, void* __restrict__ out) {
  __shared__ u16 As[128 * 32];
  __shared__ u16 Bs[128 * 32];
  const int tid = threadIdx.x;
  const int w = tid >> 6, lane = tid & 63;
  const int wr = w >> 1, wc = w & 1;
  const int l16 = lane & 15, lhi = lane >> 4;
  const int m0 = blockIdx.y * 128, n0 = blockIdx.x * 128;

  f32x4 acc[4][4] = {};

  for (int kt = 0; kt < 32; ++kt) {
    #pragma unroll
    for (int i = 0; i < 2; ++i) {
      const int ob = w * 2048 + i * 1024;      // wave-uniform LDS byte base
      const int o = ob + (lane << 4);          // this lane's byte offset
      const int row = o >> 6, kbyte = o & 63;  // [128][32] bf16: 64B rows
      gload_lds16((const char*)A + (((size_t)(m0 + row)) << 11) + (kt << 6) + kbyte,
                  (char*)As + ob);
      gload_lds16((const char*)BT + (((size_t)(n0 + row)) << 11) + (kt << 6) + kbyte,
                  (char*)Bs + ob);
    }
    __syncthreads();
    bf16x8 a[4], b[4];
    #pragma unroll
    for (int i = 0; i < 4; ++i)
      a[i] = *(const bf16x8*)(As + (wr * 64 + i * 16 + l16) * 32 + lhi * 8);
    #pragma unroll
    for (int j = 0; j < 4; ++j)
      b[j] = *(const bf16x8*)(Bs + (wc * 64 + j * 16 + l16) * 32 + lhi * 8);
    #pragma unroll
    for (int i = 0; i < 4; ++i)
      #pragma unroll
      for (int j = 0; j < 4; ++j)
        acc[i][j] = __builtin_amdgcn_mfma_f32_16x16x32_bf16(a[i], b[j], acc[i][j], 0, 0, 0);
    __syncthreads();
  }

  #pragma unroll
  for (int i = 0; i < 4; ++i) {
    #pragma unroll
    for (int j = 0; j < 4; ++j) {
      const int n = n0 + wc * 64 + j * 16 + l16;
      const float bn = bias[n];
      #pragma unroll
      for (int r = 0; r < 4; ++r) {
        const int m = m0 + wr * 64 + i * 16 + lhi * 4 + r;
        float v = acc[i][j][r] + bn;
        const int bb = m >> 11, t = m & 2047, h = n >> 6, d = n & 63;
        if constexpr (MODE == 0) {
          v *= 0.125f;  // fold 1/sqrt(DK) into q
          ((u16*)out)[((((size_t)bb * 16 + h) * 2048 + t) << 6) + d] = f2bf(v);
        } else if constexpr (MODE == 1) {
          ((u16*)out)[((((size_t)bb * 16 + h) * 2048 + t) << 6) + d] = f2bf(v);
        } else if constexpr (MODE == 2) {
          ((u16*)out)[(((size_t)bb * 16 + h) * 64 + d) * 2048 + t] = f2bf(v);
        } else {
          ((float*)out)[(size_t)m * 1024 + n] = v;
        }
      }
    }
  }
}

// ---- flash attention: 1 block = (b, h, 64 q-rows); 4 waves x 16 rows --------
// Double-buffered K/V tiles (XOR-swizzled), one barrier per KV tile.
__global__ __launch_bounds__(256) void attn_kernel(
    const u16* __restrict__ qh, const u16* __restrict__ kh,
    const u16* __restrict__ vth, u16* __restrict__ outPre) {
  __shared__ u16 KV[2][2 * 64 * 64];  // [buf][ Kt(4096 u16) | Vt(4096 u16) ]
  __shared__ u16 Pl[4][16 * 64];      // per-wave P tile [qrow][key], swizzled

  const int tid = threadIdx.x, w = tid >> 6, lane = tid & 63;
  const int l16 = lane & 15, lhi = lane >> 4;
  const int qt = blockIdx.x, h = blockIdx.y, b = blockIdx.z;
  const size_t bh = (size_t)b * 16 + h;
  const u16* qb = qh + bh * (2048 * 64);
  const u16* kb = kh + bh * (2048 * 64);
  const u16* vb = vth + bh * (64 * 2048);

  const int qr0 = qt * 64 + w * 16;
  bf16x8 aq[2];
  #pragma unroll
  for (int c = 0; c < 2; ++c)
    aq[c] = *(const bf16x8*)(qb + (qr0 + l16) * 64 + c * 32 + lhi * 8);

  f32x4 acc_o[4] = {};
  float mrow[4] = {-1e30f, -1e30f, -1e30f, -1e30f};
  float lrow[4] = {0.f, 0.f, 0.f, 0.f};

  // stage KV tile `kv` into buffer `buf` with pre-swizzled global source
  auto stage = [&](int buf, int kv) {
    char* Kt = (char*)&KV[buf][0];
    char* Vt = (char*)&KV[buf][4096];
    #pragma unroll
    for (int i = 0; i < 2; ++i) {
      const int ob = w * 2048 + i * 1024;   // wave-uniform, 1024B (8-row) aligned
      const int o = ob + (lane << 4);
      const int os = swz128(o);             // permutes within the 8-row group
      // K tile: logical layout [key][128B], contiguous in global
      gload_lds16((const char*)kb + ((size_t)kv << 7) + os, Kt + ob);
      // V^T tile: logical [d][128B], global row stride 4096B
      const int dd = os >> 7, j0 = (os & 127) >> 1;
      gload_lds16((const char*)vb + ((size_t)dd << 12) + (((size_t)(kv + j0)) << 1),
                  Vt + ob);
    }
  };

  stage(0, 0);

  for (int t = 0; t < 32; ++t) {
    const int buf = t & 1;
    __syncthreads();  // staging for `buf` complete; prev compute done
    if (t < 31) stage(buf ^ 1, (t + 1) * 64);

    const char* Kt = (const char*)&KV[buf][0];
    const char* Vt = (const char*)&KV[buf][4096];

    // S = q . k^T   (q pre-scaled by 1/8)
    f32x4 s[4] = {};
    #pragma unroll
    for (int c = 0; c < 2; ++c) {
      #pragma unroll
      for (int jt = 0; jt < 4; ++jt) {
        const bf16x8 bk = *(const bf16x8*)(Kt +
            swz128((jt * 16 + l16) * 128 + c * 64 + lhi * 16));
        s[jt] = __builtin_amdgcn_mfma_f32_16x16x32_bf16(aq[c], bk, s[jt], 0, 0, 0);
      }
    }

    // online softmax; row i = (lane>>4)*4 + r, reduce across 16 lanes
    #pragma unroll
    for (int r = 0; r < 4; ++r) {
      float mx = fmaxf(fmaxf(s[0][r], s[1][r]), fmaxf(s[2][r], s[3][r]));
      #pragma unroll
      for (int dx = 1; dx < 16; dx <<= 1) mx = fmaxf(mx, __shfl_xor(mx, dx));
      const float mnew = fmaxf(mrow[r], mx);
      const float scale = __expf(mrow[r] - mnew);
      float ps = 0.f;
      #pragma unroll
      for (int jt = 0; jt < 4; ++jt) {
        const float p = __expf(s[jt][r] - mnew);
        s[jt][r] = p;
        ps += p;
      }
      #pragma unroll
      for (int dx = 1; dx < 16; dx <<= 1) ps += __shfl_xor(ps, dx);
      lrow[r] = lrow[r] * scale + ps;
      mrow[r] = mnew;
      #pragma unroll
      for (int dt = 0; dt < 4; ++dt) acc_o[dt][r] *= scale;
    }

    // P -> per-wave LDS (C-layout -> A-layout transpose), swizzled.
    // Wave-private: no block barrier needed, compiler inserts lgkmcnt waits.
    char* Pw = (char*)&Pl[w][0];
    #pragma unroll
    for (int jt = 0; jt < 4; ++jt)
      #pragma unroll
      for (int r = 0; r < 4; ++r)
        *(u16*)(Pw + swz128((lhi * 4 + r) * 128 + (jt * 16 + l16) * 2)) =
            f2bf(s[jt][r]);

    // O += P @ V
    #pragma unroll
    for (int c = 0; c < 2; ++c) {
      const bf16x8 ap = *(const bf16x8*)(Pw +
          swz128(l16 * 128 + c * 64 + lhi * 16));
      #pragma unroll
      for (int dt = 0; dt < 4; ++dt) {
        const bf16x8 bv = *(const bf16x8*)(Vt +
            swz128((dt * 16 + l16) * 128 + c * 64 + lhi * 16));
        acc_o[dt] = __builtin_amdgcn_mfma_f32_16x16x32_bf16(ap, bv, acc_o[dt], 0, 0, 0);
      }
    }
  }

  // write into the faithful-reshape layout: row = h*128 + t/16, col = (t%16)*64 + d
  #pragma unroll
  for (int dt = 0; dt < 4; ++dt) {
    #pragma unroll
    for (int r = 0; r < 4; ++r) {
      const int t = qr0 + lhi * 4 + r;
      const int d = dt * 16 + l16;
      const float v = acc_o[dt][r] / lrow[r];
      const int rr = h * 128 + (t >> 4);
      const int cc = ((t & 15) << 6) + d;
      outPre[((size_t)b * 2048 + rr) * 1024 + cc] = f2bf(v);
    }
  }
}

extern "C" void kernel_launch(void* const* d_in, const int* in_sizes, int n_in,
                              void* d_out, int out_size, void* d_ws, size_t ws_size,
                              hipStream_t stream) {
  const float* Q  = (const float*)d_in[0];
  const float* K  = (const float*)d_in[1];
  const float* V  = (const float*)d_in[2];
  const float* Wq = (const float*)d_in[3];
  const float* bq = (const float*)d_in[4];
  const float* Wk = (const float*)d_in[5];
  const float* bk = (const float*)d_in[6];
  const float* Wv = (const float*)d_in[7];
  const float* bv = (const float*)d_in[8];
  const float* Wo = (const float*)d_in[9];
  const float* bo = (const float*)d_in[10];

  char* ws = (char*)d_ws;
  const size_t ACT = 16777216;              // 8192*1024 bf16
  u16* act = (u16*)(ws);                    // reused: Qbf/Kbf/Vbf, then outPre
  u16* qhd = (u16*)(ws + ACT);
  u16* khd = (u16*)(ws + 2 * ACT);
  u16* vtd = (u16*)(ws + 3 * ACT);
  u16* wt  = (u16*)(ws + 4 * ACT);          // 2MB transposed weight

  const dim3 tb(32, 8), tg(32, 32);
  const dim3 gg(8, 64);                     // (N/128, M/128)
  const int cvtBlocks = 8388608 / 4 / 256;

  // q = (Q@Wq + bq)/8
  transpose_cvt_kernel<<<tg, tb, 0, stream>>>(Wq, wt);
  cvt_bf16_kernel<<<cvtBlocks, 256, 0, stream>>>(Q, act);
  gemm128_kernel<0><<<gg, 256, 0, stream>>>(act, wt, bq, qhd);
  // k
  transpose_cvt_kernel<<<tg, tb, 0, stream>>>(Wk, wt);
  cvt_bf16_kernel<<<cvtBlocks, 256, 0, stream>>>(K, act);
  gemm128_kernel<1><<<gg, 256, 0, stream>>>(act, wt, bk, khd);
  // v (stored transposed per head)
  transpose_cvt_kernel<<<tg, tb, 0, stream>>>(Wv, wt);
  cvt_bf16_kernel<<<cvtBlocks, 256, 0, stream>>>(V, act);
  gemm128_kernel<2><<<gg, 256, 0, stream>>>(act, wt, bv, vtd);
  // attention -> outPre (reuses act)
  attn_kernel<<<dim3(32, 16, 4), 256, 0, stream>>>(qhd, khd, vtd, act);
  // out = outPre @ Wo + bo (f32)
  transpose_cvt_kernel<<<tg, tb, 0, stream>>>(Wo, wt);
  gemm128_kernel<3><<<gg, 256, 0, stream>>>(act, wt, bo, (float*)d_out);
}